// Round 11
// baseline (406.939 us; speedup 1.0000x reference)
//
#include <hip/hip_runtime.h>
#include <hip/hip_bf16.h>
#include <math.h>

// B=4, C=256, C8=32, N=4096. ws (bf16/ushort elems):
//   qth[b][n][32], qtl, kth, ktl   (4 x 524288)
//   vh[b][e][n], vl                (2 x 4194304)      total 20.97 MB
typedef __attribute__((ext_vector_type(8))) short bf16x8;
typedef __attribute__((ext_vector_type(4))) float f32x4;
typedef unsigned short ushort;
typedef unsigned int uint;

#define F4(p)  (*reinterpret_cast<float4*>(p))
#define CF4(p) (*reinterpret_cast<const float4*>(p))

__device__ __forceinline__ float bf2f(ushort h) {
    return __uint_as_float(((uint)h) << 16);
}
__device__ __forceinline__ ushort f2bf(float f) {        // RNE via HW cvt
    __hip_bfloat16 h = __float2bfloat16(f);
    ushort u; __builtin_memcpy(&u, &h, 2); return u;
}
__device__ __forceinline__ uint packbf2(float a, float b) {  // v_cvt_pk_bf16_f32
    __hip_bfloat162 h2 = __float22bfloat162_rn(make_float2(a, b));
    uint u; __builtin_memcpy(&u, &h2, 4); return u;
}

// ---------------------------------------------------------------------------
// Projection GEMM (fp32) -> bf16 hi/lo. n-tile 16, grid 1024 -> 4 blocks/CU
// (LDS 20.7 KB). Same per-output c-order as before -> bit-identical results.
// ---------------------------------------------------------------------------
__global__ __launch_bounds__(256) void proj_kernel(
    const float* __restrict__ x,
    const float* __restrict__ wq, const float* __restrict__ bq,
    const float* __restrict__ wk, const float* __restrict__ bk,
    const float* __restrict__ wv, const float* __restrict__ bv,
    ushort* __restrict__ ws)
{
    ushort* qth = ws;
    ushort* qtl = qth + 524288;
    ushort* kth = qtl + 524288;
    ushort* ktl = kth + 524288;
    ushort* vhp = ktl + 524288;
    ushort* vlp = vhp + 4194304;

    __shared__ float Xt[16][260];                 // [n][c]
    __shared__ __align__(16) ushort Oh[1024];
    __shared__ __align__(16) ushort Ol[1024];

    const int t   = threadIdx.x;
    const int blk = blockIdx.x;                   // 1024 = 4b x 256 n-tiles
    const int b   = blk >> 8;
    const int n0  = (blk & 255) * 16;

    {   // stage x[b][:, n0..n0+15] transposed
        const int tn4 = (t & 3) * 4;
        const int c0  = t >> 2;                   // 0..63
        #pragma unroll
        for (int p = 0; p < 4; ++p) {
            const int c = c0 + (p << 6);
            const float4 xv = CF4(&x[(((size_t)b * 256 + c) << 12) + n0 + tn4]);
            Xt[tn4 + 0][c] = xv.x;
            Xt[tn4 + 1][c] = xv.y;
            Xt[tn4 + 2][c] = xv.z;
            Xt[tn4 + 3][c] = xv.w;
        }
    }
    __syncthreads();

    const int td = t >> 4;    // 0..15 (row quarter)
    const int tn = t & 15;    // 0..15 (n within tile)

    for (int g = 0; g < 5; ++g) {
        const int d0 = g * 64;
        float acc[4] = {0.f, 0.f, 0.f, 0.f};

        const float* wrow[4];
        float bias[4];
        #pragma unroll
        for (int dd = 0; dd < 4; ++dd) {
            const int rr = d0 + td + (dd << 4);
            if (rr < 32)      { wrow[dd] = wq + rr * 256;        bias[dd] = bq[rr]; }
            else if (rr < 64) { wrow[dd] = wk + (rr - 32) * 256; bias[dd] = bk[rr - 32]; }
            else              { wrow[dd] = wv + (rr - 64) * 256; bias[dd] = bv[rr - 64]; }
        }

        for (int c = 0; c < 256; c += 4) {
            const float4 xv = CF4(&Xt[tn][c]);
            #pragma unroll
            for (int dd = 0; dd < 4; ++dd) {
                const float4 w4 = CF4(&wrow[dd][c]);
                acc[dd] += w4.x * xv.x + w4.y * xv.y + w4.z * xv.z + w4.w * xv.w;
            }
        }

        #pragma unroll
        for (int dd = 0; dd < 4; ++dd) {
            const int rr  = d0 + td + (dd << 4);
            const float val = acc[dd] + bias[dd];
            const ushort h  = f2bf(val);
            const ushort lo = f2bf(val - bf2f(h));
            int o;
            if (g == 0) o = (rr < 32) ? tn * 32 + rr : 512 + tn * 32 + (rr - 32);
            else        o = (rr - d0) * 16 + tn;
            Oh[o] = h; Ol[o] = lo;
        }
        __syncthreads();      // tile complete

        // flush 1024 ushorts: uint2 (8B) per thread, thread-contiguous
        {
            const int o = t * 4;
            const uint2 vh = *reinterpret_cast<uint2*>(&Oh[o]);
            const uint2 vl = *reinterpret_cast<uint2*>(&Ol[o]);
            if (g == 0) {
                const size_t qb = ((size_t)(b * 4096 + n0)) * 32;
                if (o < 512) {
                    *reinterpret_cast<uint2*>(&qth[qb + o]) = vh;
                    *reinterpret_cast<uint2*>(&qtl[qb + o]) = vl;
                } else {
                    *reinterpret_cast<uint2*>(&kth[qb + o - 512]) = vh;
                    *reinterpret_cast<uint2*>(&ktl[qb + o - 512]) = vl;
                }
            } else {
                const size_t vb = ((size_t)(b * 256 + (g - 1) * 64)) * 4096 + n0;
                const size_t ga = vb + (size_t)(o >> 4) * 4096 + (o & 15);
                *reinterpret_cast<uint2*>(&vhp[ga]) = vh;
                *reinterpret_cast<uint2*>(&vlp[ga]) = vl;
            }
        }
        __syncthreads();      // flush done before next group's LDS writes
    }
}

// ---------------------------------------------------------------------------
// Flash attention via bf16 MFMA (hi/lo, 3-term). Grid 512, 4 waves/block,
// 2 blocks/CU. Pipeline: V-frag loads issued at iter top (used after
// barrier); K frags prefetched for jt+1 during PV; P/fac double-buffered
// -> ONE barrier per jt. MFMA order unchanged -> bit-identical to R5.
// ---------------------------------------------------------------------------
__global__ __launch_bounds__(256, 2) void attn_kernel(
    const ushort* __restrict__ ws,
    const float* __restrict__ x,
    const float* __restrict__ gamma,
    float* __restrict__ out)
{
    const ushort* qth = ws;
    const ushort* qtl = qth + 524288;
    const ushort* kth = qtl + 524288;
    const ushort* ktl = kth + 524288;
    const ushort* vhp = ktl + 524288;
    const ushort* vlp = vhp + 4194304;

    __shared__ __align__(16) ushort Ph[2][4096];   // [buf][i][j^((i&7)<<3)]
    __shared__ __align__(16) ushort Pl[2][4096];
    __shared__ float fac_sh[2][64];
    __shared__ float l_sh[64];

    const int t    = threadIdx.x;
    const int w    = t >> 6;
    const int lane = t & 63;
    const int m    = lane & 15;
    const int gr   = lane >> 4;

    const int blk = blockIdx.x;
    const int e8  = blk & 7;
    const int g_  = blk >> 3;                 // 0..63
    const int b   = e8 >> 1;
    const int i0  = ((g_ & 31) + ((e8 & 1) << 5)) << 6;
    const int ebase = ((g_ >> 5) << 7) + w * 32;

    const size_t qkbase = (size_t)b * 4096 * 32;
    const size_t vbase  = (size_t)b * 256 * 4096;

    const int iq = i0 + w * 16 + m;
    const bf16x8 qbh = *(const bf16x8*)(qth + qkbase + (size_t)iq * 32 + 8 * gr);
    const bf16x8 qbl = *(const bf16x8*)(qtl + qkbase + (size_t)iq * 32 + 8 * gr);

    f32x4 accv[2][4];
    #pragma unroll
    for (int a = 0; a < 2; ++a)
        #pragma unroll
        for (int c = 0; c < 4; ++c) accv[a][c] = f32x4{0.f, 0.f, 0.f, 0.f};

    float m_run = -INFINITY, l_run = 0.f;
    const int irow = w * 16 + m;

    // prologue: K fragments for jt=0
    bf16x8 kh[4], kl[4];
    #pragma unroll
    for (int mf = 0; mf < 4; ++mf) {
        const size_t ko = qkbase + (size_t)(mf * 16 + m) * 32 + 8 * gr;
        kh[mf] = *(const bf16x8*)(kth + ko);
        kl[mf] = *(const bf16x8*)(ktl + ko);
    }

    for (int jt = 0; jt < 64; ++jt) {
        const int j0  = jt << 6;
        const int buf = jt & 1;

        // --- V fragment loads for THIS jt (issue early, consume after barrier)
        bf16x8 vh_r[4], vl_r[4];
        #pragma unroll
        for (int ks = 0; ks < 2; ++ks)
            #pragma unroll
            for (int mf = 0; mf < 2; ++mf) {
                const size_t vo = vbase + (size_t)(ebase + mf * 16 + m) * 4096
                                + j0 + ks * 32 + 8 * gr;
                vh_r[ks * 2 + mf] = *(const bf16x8*)(vhp + vo);
                vl_r[ks * 2 + mf] = *(const bf16x8*)(vlp + vo);
            }

        // --- S^T = K·Q (3-term hi/lo), K from prefetched regs ---
        f32x4 st[4];
        #pragma unroll
        for (int mf = 0; mf < 4; ++mf) {
            f32x4 a = {0.f, 0.f, 0.f, 0.f};
            a = __builtin_amdgcn_mfma_f32_16x16x32_bf16(kh[mf], qbh, a, 0, 0, 0);
            a = __builtin_amdgcn_mfma_f32_16x16x32_bf16(kh[mf], qbl, a, 0, 0, 0);
            a = __builtin_amdgcn_mfma_f32_16x16x32_bf16(kl[mf], qbh, a, 0, 0, 0);
            st[mf] = a;
        }

        // --- online softmax ---
        float tm = st[0][0];
        #pragma unroll
        for (int mf = 0; mf < 4; ++mf)
            #pragma unroll
            for (int r = 0; r < 4; ++r) tm = fmaxf(tm, st[mf][r]);
        tm = fmaxf(tm, __shfl_xor(tm, 16));
        tm = fmaxf(tm, __shfl_xor(tm, 32));
        const float m_new = fmaxf(m_run, tm);
        const float fac   = __expf(m_run - m_new);
        float p[4][4];
        float ts = 0.f;
        #pragma unroll
        for (int mf = 0; mf < 4; ++mf)
            #pragma unroll
            for (int r = 0; r < 4; ++r) {
                p[mf][r] = __expf(st[mf][r] - m_new);
                ts += p[mf][r];
            }
        ts += __shfl_xor(ts, 16);
        ts += __shfl_xor(ts, 32);
        l_run = l_run * fac + ts;
        m_run = m_new;

        // --- P hi/lo via cvt_pk, write to buffer `buf` ---
        #pragma unroll
        for (int mf = 0; mf < 4; ++mf) {
            const int j    = mf * 16 + 4 * gr;
            const int addr = irow * 64 + (j ^ ((irow & 7) << 3));
            const uint h01 = packbf2(p[mf][0], p[mf][1]);
            const uint h23 = packbf2(p[mf][2], p[mf][3]);
            const float r0 = p[mf][0] - bf2f((ushort)h01);
            const float r1 = p[mf][1] - bf2f((ushort)(h01 >> 16));
            const float r2 = p[mf][2] - bf2f((ushort)h23);
            const float r3 = p[mf][3] - bf2f((ushort)(h23 >> 16));
            *reinterpret_cast<uint2*>(&Ph[buf][addr]) = make_uint2(h01, h23);
            *reinterpret_cast<uint2*>(&Pl[buf][addr]) =
                make_uint2(packbf2(r0, r1), packbf2(r2, r3));
        }
        if (gr == 0) fac_sh[buf][irow] = fac;

        // --- prefetch K fragments for jt+1 (wraps harmlessly at jt=63) ---
        const int jn0 = ((jt + 1) & 63) << 6;
        bf16x8 kh_n[4], kl_n[4];
        #pragma unroll
        for (int mf = 0; mf < 4; ++mf) {
            const size_t ko = qkbase + (size_t)(jn0 + mf * 16 + m) * 32 + 8 * gr;
            kh_n[mf] = *(const bf16x8*)(kth + ko);
            kl_n[mf] = *(const bf16x8*)(ktl + ko);
        }

        __syncthreads();                      // P + fac ready (single barrier)

        // --- rescale ---
        float fc[4];
        #pragma unroll
        for (int f = 0; f < 4; ++f) fc[f] = fac_sh[buf][f * 16 + m];
        #pragma unroll
        for (int mf = 0; mf < 2; ++mf)
            #pragma unroll
            for (int f = 0; f < 4; ++f)
                #pragma unroll
                for (int r = 0; r < 4; ++r) accv[mf][f][r] *= fc[f];

        // --- PV (V from regs, P from LDS buffer `buf`) ---
        #pragma unroll
        for (int ks = 0; ks < 2; ++ks) {
            bf16x8 pbh[4], pbl[4];
            #pragma unroll
            for (int f = 0; f < 4; ++f) {
                const int i_   = f * 16 + m;
                const int j    = ks * 32 + 8 * gr;
                const int addr = i_ * 64 + (j ^ ((i_ & 7) << 3));
                pbh[f] = *reinterpret_cast<const bf16x8*>(&Ph[buf][addr]);
                pbl[f] = *reinterpret_cast<const bf16x8*>(&Pl[buf][addr]);
            }
            #pragma unroll
            for (int mf = 0; mf < 2; ++mf) {
                const bf16x8 vah = vh_r[ks * 2 + mf];
                const bf16x8 val = vl_r[ks * 2 + mf];
                #pragma unroll
                for (int f = 0; f < 4; ++f) {
                    accv[mf][f] = __builtin_amdgcn_mfma_f32_16x16x32_bf16(vah, pbh[f], accv[mf][f], 0, 0, 0);
                    accv[mf][f] = __builtin_amdgcn_mfma_f32_16x16x32_bf16(vah, pbl[f], accv[mf][f], 0, 0, 0);
                    accv[mf][f] = __builtin_amdgcn_mfma_f32_16x16x32_bf16(val, pbh[f], accv[mf][f], 0, 0, 0);
                }
            }
        }

        // roll K prefetch
        #pragma unroll
        for (int mf = 0; mf < 4; ++mf) { kh[mf] = kh_n[mf]; kl[mf] = kl_n[mf]; }
    }

    if (gr == 0) l_sh[irow] = l_run;
    __syncthreads();

    const float gv = gamma[0];
    float sc[4];
    #pragma unroll
    for (int f = 0; f < 4; ++f) sc[f] = gv / l_sh[f * 16 + m];
    #pragma unroll
    for (int mf = 0; mf < 2; ++mf)
        #pragma unroll
        for (int f = 0; f < 4; ++f)
            #pragma unroll
            for (int r = 0; r < 4; ++r) {
                const int e = ebase + mf * 16 + 4 * gr + r;
                const int i = i0 + f * 16 + m;
                const size_t idx = ((size_t)b * 256 + e) * 4096 + i;
                out[idx] = accv[mf][f][r] * sc[f] + x[idx];
            }
}

extern "C" void kernel_launch(void* const* d_in, const int* in_sizes, int n_in,
                              void* d_out, int out_size, void* d_ws, size_t ws_size,
                              hipStream_t stream) {
    const float* x     = (const float*)d_in[0];
    const float* wq    = (const float*)d_in[1];
    const float* bq    = (const float*)d_in[2];
    const float* wk    = (const float*)d_in[3];
    const float* bk    = (const float*)d_in[4];
    const float* wv    = (const float*)d_in[5];
    const float* bv    = (const float*)d_in[6];
    const float* gamma = (const float*)d_in[7];
    float* out  = (float*)d_out;
    ushort* ws  = (ushort*)d_ws;    // 10.5M ushorts = 20.97 MB

    proj_kernel<<<1024, 256, 0, stream>>>(x, wq, bq, wk, bk, wv, bv, ws);
    attn_kernel<<<512, 256, 0, stream>>>(ws, x, gamma, out);
}